// Round 5
// baseline (198.716 us; speedup 1.0000x reference)
//
#include <hip/hip_runtime.h>
#include <hip/hip_bf16.h>

typedef __attribute__((ext_vector_type(8))) short short8;
typedef __attribute__((ext_vector_type(4))) float f32x4;

#define ALPHA 0.2f
#define NEG_INF -9e15f
#define OUT_ROWS 126
#define NTILES 521            // ceil(65536/126)
#define NB 4
#define NN 65536
#define TOT (NTILES * NB)     // 2084
#define GRID 512              // persistent, 2 blocks/CU

__device__ __forceinline__ short fb(float x) {
    __hip_bfloat16 b = __float2bfloat16(x);
    return __builtin_bit_cast(short, b);
}
__device__ __forceinline__ float bf2f(unsigned short x) {
    union { unsigned int u; float f; } v; v.u = ((unsigned int)x) << 16;
    return v.f;
}

// ---- prep: W -> bf16 B-fragment table; [Wa1 Wa2 0..] -> B2 fragment table ----
__global__ __launch_bounds__(256) void prep_w(const float* __restrict__ W,
                                              const float* __restrict__ a,
                                              unsigned short* __restrict__ ws) {
    const int t = threadIdx.x;
    if (blockIdx.x < 8) {
        int q = blockIdx.x * 256 + t;
        int lane = q & 63, fi = q >> 6;
        int ni = fi & 3, kk = (fi >> 2) & 3, wcg = fi >> 4;
        int n = wcg * 64 + ni * 16 + (lane & 15);
        int k0 = kk * 32 + ((lane >> 4) & 3) * 8;
        short8 o;
        #pragma unroll
        for (int j = 0; j < 8; ++j) o[j] = fb(W[(k0 + j) * 128 + n]);
        *(short8*)(ws + (size_t)q * 8) = o;
    } else {
        __shared__ float wa[2][128];
        {
            int k = t >> 1, sel = t & 1;
            const f32x4* wr4 = (const f32x4*)(W + k * 128);
            const f32x4* av4 = (const f32x4*)(a + sel * 128);
            float s = 0.f;
            #pragma unroll
            for (int c4 = 0; c4 < 32; ++c4) {
                f32x4 wv = wr4[c4], av = av4[c4];
                s += wv[0]*av[0] + wv[1]*av[1] + wv[2]*av[2] + wv[3]*av[3];
            }
            wa[sel][k] = s;
        }
        __syncthreads();
        {
            int lane = t & 63, kk = t >> 6;
            int l15 = lane & 15, lg = (lane >> 4) & 3;
            int k0 = kk * 32 + lg * 8;
            short8 o;
            #pragma unroll
            for (int j = 0; j < 8; ++j) o[j] = fb((l15 < 2) ? wa[l15][k0 + j] : 0.f);
            *(short8*)(ws + 16384 + (size_t)t * 8) = o;
        }
    }
}

// Persistent 2-barrier pipelined kernel. Fixed-role LDS: Ah = current h tile
// (bf16 swizzled), Bw = current Wh tile (bf16 swizzled). Next tile's h loads
// are issued at iter top (held in regs) and written to Ah at iter end.
__global__ __launch_bounds__(256, 2)
void gat_fused(const float* __restrict__ h, const int* __restrict__ opm,
               const unsigned short* __restrict__ ws, float* __restrict__ out) {
    __shared__ __align__(16) char Ah[32768];
    __shared__ __align__(16) char Bw[32768];
    __shared__ float wh1s[128];
    __shared__ float wh2s[136];               // row r stored at 4+r

    const int t = threadIdx.x;
    const int lane = t & 63;
    const int wave = t >> 6;
    const int l15 = lane & 15;
    const int lg = (lane >> 4) & 3;
    const int wr = (wave >> 1) << 6;          // row band 0 / 64
    const int wcg = wave & 1;
    const int wc = wcg << 6;                  // col band 0 / 64

    const short8* wsv  = (const short8*)ws;
    const short8* wsv2 = (const short8*)(ws + 16384);

    // ---- prologue: stage first tile into Ah ----
    {
        int ti = blockIdx.x;
        int b = ti / NTILES;
        int tile = ti - b * NTILES;
        int base = tile * OUT_ROWS - 1;
        const float* hB = h + (size_t)b * NN * 128;
        f32x4 s[16];
        #pragma unroll
        for (int i = 0; i < 16; ++i) {
            int rl = (wave << 5) + (i << 1) + (lane >> 5);
            int g = base + rl; if (g < 0) g += NN; else if (g >= NN) g -= NN;
            s[i] = *(const f32x4*)(hB + (size_t)g * 128 + ((lane & 31) << 2));
        }
        #pragma unroll
        for (int i = 0; i < 16; ++i) {
            int rl = (wave << 5) + (i << 1) + (lane >> 5);
            ushort4 p4;
            p4.x = (unsigned short)fb(s[i][0]);
            p4.y = (unsigned short)fb(s[i][1]);
            p4.z = (unsigned short)fb(s[i][2]);
            p4.w = (unsigned short)fb(s[i][3]);
            *(ushort4*)(&Ah[rl * 256 + ((((lane & 31) << 3)) ^ ((rl & 7) << 4))]) = p4;
        }
    }
    __syncthreads();

    for (int ti = blockIdx.x; ti < TOT; ti += GRID) {
        const int b = ti / NTILES;
        const int tile = ti - b * NTILES;
        const int row_start = tile * OUT_ROWS;
        const int base = row_start - 1;
        const int out_rows = min(OUT_ROWS, NN - row_start);
        float* outB = out + (size_t)b * NN * 128;
        const int* opmB = opm + (size_t)b * NN * 3;

        // ---- issue next tile's h loads (in flight across whole compute) ----
        const int tn = ti + GRID;
        const bool hn = tn < TOT;
        f32x4 sreg[16];
        if (hn) {
            int b2 = tn / NTILES;
            int tile2 = tn - b2 * NTILES;
            int base2 = tile2 * OUT_ROWS - 1;
            const float* hB2 = h + (size_t)b2 * NN * 128;
            #pragma unroll
            for (int i = 0; i < 16; ++i) {
                int rl = (wave << 5) + (i << 1) + (lane >> 5);
                int g = base2 + rl; if (g < 0) g += NN; else if (g >= NN) g -= NN;
                sreg[i] = *(const f32x4*)(hB2 + (size_t)g * 128 + ((lane & 31) << 2));
            }
        }
        __builtin_amdgcn_sched_barrier(0);   // pin load issue above compute

        // ---- GEMM on Ah (B frags streamed from L2/L3-hot ws) ----
        f32x4 acc[4][4];
        f32x4 acc2[4];
        #pragma unroll
        for (int mi = 0; mi < 4; ++mi) {
            acc2[mi] = (f32x4){0.f, 0.f, 0.f, 0.f};
            #pragma unroll
            for (int ni = 0; ni < 4; ++ni)
                acc[mi][ni] = (f32x4){0.f, 0.f, 0.f, 0.f};
        }
        #pragma unroll
        for (int kk = 0; kk < 4; ++kk) {
            short8 bfr[4], bfr2;
            #pragma unroll
            for (int ni = 0; ni < 4; ++ni)
                bfr[ni] = wsv[((((wcg << 2) + kk) << 2) + ni) * 64 + lane];
            bfr2 = wsv2[(kk << 6) + lane];
            int kb = (kk << 6) + (lg << 4);
            short8 af[4];
            #pragma unroll
            for (int mi = 0; mi < 4; ++mi) {
                int m = wr + (mi << 4) + l15;
                af[mi] = *(const short8*)(&Ah[m * 256 + (kb ^ ((m & 7) << 4))]);
            }
            #pragma unroll
            for (int mi = 0; mi < 4; ++mi)
                #pragma unroll
                for (int ni = 0; ni < 4; ++ni)
                    acc[mi][ni] = __builtin_amdgcn_mfma_f32_16x16x32_bf16(
                        af[mi], bfr[ni], acc[mi][ni], 0, 0, 0);
            if (wcg == 0) {
                #pragma unroll
                for (int mi = 0; mi < 4; ++mi)
                    acc2[mi] = __builtin_amdgcn_mfma_f32_16x16x32_bf16(
                        af[mi], bfr2, acc2[mi], 0, 0, 0);
            }
        }

        // ---- spill Wh (bf16, swizzled) into Bw; wh1/wh2 from acc2 ----
        #pragma unroll
        for (int mi = 0; mi < 4; ++mi)
            #pragma unroll
            for (int ni = 0; ni < 4; ++ni) {
                int col = wc + (ni << 4) + l15;
                #pragma unroll
                for (int j = 0; j < 4; ++j) {
                    int row = wr + (mi << 4) + (lg << 2) + j;
                    *(unsigned short*)(&Bw[row * 256 + ((col << 1) ^ ((row & 7) << 4))]) =
                        (unsigned short)fb(acc[mi][ni][j]);
                }
            }
        if (wcg == 0 && l15 < 2) {
            float* dst = (l15 == 0) ? wh1s : (wh2s + 4);
            #pragma unroll
            for (int mi = 0; mi < 4; ++mi)
                #pragma unroll
                for (int j = 0; j < 4; ++j)
                    dst[wr + (mi << 4) + (lg << 2) + j] = acc2[mi][j];
        }
        __syncthreads();

        // ---- combine: inline softmax (free SIMT redundancy) + row stores ----
        #pragma unroll
        for (int it = 0; it < 16; ++it) {
            int r = 1 + (t >> 5) + (it << 3);
            if (r > out_rows) continue;
            int g = base + r;
            const int* mrow = opmB + (size_t)g * 3;
            int mk0 = mrow[0], mk1 = mrow[1], mk2 = mrow[2];
            float w1 = wh1s[r];
            float e0 = w1 + wh2s[3 + r];
            float e1 = w1 + wh2s[4 + r];
            float e2 = w1 + wh2s[5 + r];
            e0 = e0 > 0.f ? e0 : ALPHA * e0;
            e1 = e1 > 0.f ? e1 : ALPHA * e1;
            e2 = e2 > 0.f ? e2 : ALPHA * e2;
            if (mk0 > 0) e0 = NEG_INF;
            if (mk1 > 0) e1 = NEG_INF;
            if (mk2 > 0) e2 = NEG_INF;
            float m = fmaxf(e0, fmaxf(e1, e2));
            float x0 = __expf(e0 - m), x1 = __expf(e1 - m), x2 = __expf(e2 - m);
            float inv = 1.f / (x0 + x1 + x2);
            float a0 = x0 * inv, a1 = x1 * inv, a2 = x2 * inv;
            int cb = (t & 31) << 3;
            ushort4 wm = *(const ushort4*)(&Bw[(r - 1) * 256 + (cb ^ (((r - 1) & 7) << 4))]);
            ushort4 w0 = *(const ushort4*)(&Bw[r * 256 + (cb ^ ((r & 7) << 4))]);
            ushort4 wp = *(const ushort4*)(&Bw[(r + 1) * 256 + (cb ^ (((r + 1) & 7) << 4))]);
            f32x4 res;
            res[0] = a0 * bf2f(wm.x) + a1 * bf2f(w0.x) + a2 * bf2f(wp.x);
            res[1] = a0 * bf2f(wm.y) + a1 * bf2f(w0.y) + a2 * bf2f(wp.y);
            res[2] = a0 * bf2f(wm.z) + a1 * bf2f(w0.z) + a2 * bf2f(wp.z);
            res[3] = a0 * bf2f(wm.w) + a1 * bf2f(w0.w) + a2 * bf2f(wp.w);
            *(f32x4*)(outB + (size_t)g * 128 + ((t & 31) << 2)) = res;
        }

        // ---- write staged next tile into Ah ----
        if (hn) {
            #pragma unroll
            for (int i = 0; i < 16; ++i) {
                int rl = (wave << 5) + (i << 1) + (lane >> 5);
                ushort4 p4;
                p4.x = (unsigned short)fb(sreg[i][0]);
                p4.y = (unsigned short)fb(sreg[i][1]);
                p4.z = (unsigned short)fb(sreg[i][2]);
                p4.w = (unsigned short)fb(sreg[i][3]);
                *(ushort4*)(&Ah[rl * 256 + ((((lane & 31) << 3)) ^ ((rl & 7) << 4))]) = p4;
            }
        }
        __syncthreads();
    }
}

extern "C" void kernel_launch(void* const* d_in, const int* in_sizes, int n_in,
                              void* d_out, int out_size, void* d_ws, size_t ws_size,
                              hipStream_t stream) {
    const float* h   = (const float*)d_in[0];
    const int*   opm = (const int*)d_in[1];
    const float* W   = (const float*)d_in[2];
    const float* a   = (const float*)d_in[3];
    float* out = (float*)d_out;
    unsigned short* ws = (unsigned short*)d_ws;
    prep_w<<<9, 256, 0, stream>>>(W, a, ws);
    gat_fused<<<GRID, 256, 0, stream>>>(h, opm, ws, out);
}

// Round 6
// 157.896 us; speedup vs baseline: 1.2585x; 1.2585x over previous
//
#include <hip/hip_runtime.h>
#include <hip/hip_bf16.h>

typedef __attribute__((ext_vector_type(8))) short short8;
typedef __attribute__((ext_vector_type(4))) float f32x4;

#define ALPHA 0.2f
#define NEG_INF -9e15f
#define OUT_ROWS 126
#define NTILES 521            // ceil(65536/126)
#define NB 4
#define NN 65536
#define TOT (NTILES * NB)     // 2084
#define GRID 512              // persistent, 2 blocks/CU (512 thr)

__device__ __forceinline__ short fb(float x) {
    __hip_bfloat16 b = __float2bfloat16(x);
    return __builtin_bit_cast(short, b);
}
__device__ __forceinline__ float bf2f(unsigned short x) {
    union { unsigned int u; float f; } v; v.u = ((unsigned int)x) << 16;
    return v.f;
}

// prep: W -> bf16 B-fragment table (32 frags: fi = kk*8 + q, q = col16 block);
//       va1 = W@a1, va2 = W@a2 as f32[2][128] at byte 32768.
__global__ __launch_bounds__(256) void prep_w(const float* __restrict__ W,
                                              const float* __restrict__ a,
                                              unsigned short* __restrict__ ws) {
    const int t = threadIdx.x;
    if (blockIdx.x < 8) {
        int qg = blockIdx.x * 256 + t;       // 0..2047
        int lane = qg & 63, fi = qg >> 6;    // fi 0..31
        int q = fi & 7, kk = fi >> 3;
        int n = q * 16 + (lane & 15);
        int k0 = kk * 32 + ((lane >> 4) & 3) * 8;
        short8 o;
        #pragma unroll
        for (int j = 0; j < 8; ++j) o[j] = fb(W[(k0 + j) * 128 + n]);
        *(short8*)(ws + (size_t)qg * 8) = o;
    } else {
        int k = t >> 1, sel = t & 1;
        const f32x4* wr4 = (const f32x4*)(W + k * 128);
        const f32x4* av4 = (const f32x4*)(a + sel * 128);
        float s = 0.f;
        #pragma unroll
        for (int c4 = 0; c4 < 32; ++c4) {
            f32x4 wv = wr4[c4], av = av4[c4];
            s += wv[0]*av[0] + wv[1]*av[1] + wv[2]*av[2] + wv[3]*av[3];
        }
        float* va = (float*)((char*)ws + 32768);
        va[sel * 128 + k] = s;
    }
}

// Persistent 2-barrier pipelined kernel, 512 threads (8 waves).
// Fixed-role LDS: Ah = current h tile (bf16 swizzled), Bw = Wh tile (bf16).
// Phase A: issue next-tile loads; wh1/wh2 dots; GEMM; spill->Bw.  bar.
// Phase B: combine(+inline softmax)+store; cvt staged regs -> Ah.  bar.
__global__ __launch_bounds__(512, 4)
void gat_fused(const float* __restrict__ h, const int* __restrict__ opm,
               const unsigned short* __restrict__ ws, float* __restrict__ out) {
    __shared__ __align__(16) char Ah[32768];
    __shared__ __align__(16) char Bw[32768];
    __shared__ float wh1s[128];
    __shared__ float wh2s[136];               // row r at index 4+r
    __shared__ float va1s[128];
    __shared__ float va2s[128];

    const int t = threadIdx.x;
    const int lane = t & 63;
    const int w = t >> 6;                     // 0..7
    const int l15 = lane & 15;
    const int lg = (lane >> 4) & 3;
    const int R = (w >> 2) << 6;              // row band 0 / 64
    const int C = (w & 3) << 5;               // col quad 0/32/64/96

    // va vectors to LDS
    if (t < 256) {
        const float* va = (const float*)((const char*)ws + 32768);
        if (t < 128) va1s[t] = va[t]; else va2s[t - 128] = va[t];
    }

    // ---- prologue: stage first tile into Ah ----
    {
        int ti = blockIdx.x;
        int b = ti / NTILES;
        int tile = ti - b * NTILES;
        int base = tile * OUT_ROWS - 1;
        const float* hB = h + (size_t)b * NN * 128;
        f32x4 s[8];
        #pragma unroll
        for (int i = 0; i < 8; ++i) {
            int rl = (w << 4) + (i << 1) + (lane >> 5);
            int g = base + rl; if (g < 0) g += NN; else if (g >= NN) g -= NN;
            s[i] = *(const f32x4*)(hB + (size_t)g * 128 + ((lane & 31) << 2));
        }
        #pragma unroll
        for (int i = 0; i < 8; ++i) {
            int rl = (w << 4) + (i << 1) + (lane >> 5);
            ushort4 p4;
            p4.x = (unsigned short)fb(s[i][0]);
            p4.y = (unsigned short)fb(s[i][1]);
            p4.z = (unsigned short)fb(s[i][2]);
            p4.w = (unsigned short)fb(s[i][3]);
            *(ushort4*)(&Ah[rl * 256 + ((((lane & 31) << 3)) ^ ((rl & 7) << 4))]) = p4;
        }
    }
    __syncthreads();

    const short8* wsv = (const short8*)ws;

    for (int ti = blockIdx.x; ti < TOT; ti += GRID) {
        const int b = ti / NTILES;
        const int tile = ti - b * NTILES;
        const int row_start = tile * OUT_ROWS;
        const int base = row_start - 1;
        const int out_rows = min(OUT_ROWS, NN - row_start);
        float* outB = out + (size_t)b * NN * 128;
        const int* opmB = opm + (size_t)b * NN * 3;

        // ---- issue next tile's h loads (land during this tile's compute) ----
        const int tn = ti + GRID;
        const bool hn = tn < TOT;
        f32x4 sreg[8];
        if (hn) {
            int b2 = tn / NTILES;
            int tile2 = tn - b2 * NTILES;
            int base2 = tile2 * OUT_ROWS - 1;
            const float* hB2 = h + (size_t)b2 * NN * 128;
            #pragma unroll
            for (int i = 0; i < 8; ++i) {
                int rl = (w << 4) + (i << 1) + (lane >> 5);
                int g = base2 + rl; if (g < 0) g += NN; else if (g >= NN) g -= NN;
                sreg[i] = *(const f32x4*)(hB2 + (size_t)g * 128 + ((lane & 31) << 2));
            }
        }
        __builtin_amdgcn_sched_barrier(0);    // keep load issue above compute

        // ---- wh1/wh2 dots from Ah (4 threads per row, 32 cols each) ----
        {
            int row = t >> 2;
            int cb = (t & 3) << 5;
            float s1 = 0.f, s2 = 0.f;
            #pragma unroll
            for (int c8 = 0; c8 < 4; ++c8) {
                int col = cb + (c8 << 3);
                short8 hv = *(const short8*)(&Ah[row * 256 + ((col << 1) ^ ((row & 7) << 4))]);
                const f32x4 v1a = *(const f32x4*)(&va1s[col]);
                const f32x4 v1b = *(const f32x4*)(&va1s[col + 4]);
                const f32x4 v2a = *(const f32x4*)(&va2s[col]);
                const f32x4 v2b = *(const f32x4*)(&va2s[col + 4]);
                #pragma unroll
                for (int j = 0; j < 4; ++j) {
                    float x = bf2f((unsigned short)hv[j]);
                    s1 += x * v1a[j]; s2 += x * v2a[j];
                }
                #pragma unroll
                for (int j = 0; j < 4; ++j) {
                    float x = bf2f((unsigned short)hv[4 + j]);
                    s1 += x * v1b[j]; s2 += x * v2b[j];
                }
            }
            s1 += __shfl_xor(s1, 1); s1 += __shfl_xor(s1, 2);
            s2 += __shfl_xor(s2, 1); s2 += __shfl_xor(s2, 2);
            if ((t & 3) == 0) wh1s[row] = s1;
            if ((t & 3) == 1) wh2s[4 + row] = s2;
        }

        // ---- GEMM: acc[4][2] = Ah(R band) @ W(C quad) ----
        f32x4 acc[4][2];
        #pragma unroll
        for (int mi = 0; mi < 4; ++mi)
            #pragma unroll
            for (int ni = 0; ni < 2; ++ni)
                acc[mi][ni] = (f32x4){0.f, 0.f, 0.f, 0.f};
        #pragma unroll
        for (int kk = 0; kk < 4; ++kk) {
            short8 bfr[2];
            #pragma unroll
            for (int ni = 0; ni < 2; ++ni) {
                int q = ((w & 3) << 1) + ni;
                bfr[ni] = wsv[((kk << 3) + q) * 64 + lane];
            }
            int kb = (kk << 6) + (lg << 4);
            short8 af[4];
            #pragma unroll
            for (int mi = 0; mi < 4; ++mi) {
                int m = R + (mi << 4) + l15;
                af[mi] = *(const short8*)(&Ah[m * 256 + (kb ^ ((m & 7) << 4))]);
            }
            #pragma unroll
            for (int mi = 0; mi < 4; ++mi)
                #pragma unroll
                for (int ni = 0; ni < 2; ++ni)
                    acc[mi][ni] = __builtin_amdgcn_mfma_f32_16x16x32_bf16(
                        af[mi], bfr[ni], acc[mi][ni], 0, 0, 0);
        }

        // ---- spill Wh (bf16, swizzled) into Bw ----
        #pragma unroll
        for (int mi = 0; mi < 4; ++mi)
            #pragma unroll
            for (int ni = 0; ni < 2; ++ni) {
                int col = C + (ni << 4) + l15;
                #pragma unroll
                for (int j = 0; j < 4; ++j) {
                    int row = R + (mi << 4) + (lg << 2) + j;
                    *(unsigned short*)(&Bw[row * 256 + ((col << 1) ^ ((row & 7) << 4))]) =
                        (unsigned short)fb(acc[mi][ni][j]);
                }
            }
        __syncthreads();

        // ---- combine: inline softmax + coalesced row stores ----
        #pragma unroll
        for (int it = 0; it < 8; ++it) {
            int r = 1 + (t >> 5) + (it << 4);
            if (r > out_rows) continue;
            int g = base + r;
            const int* mrow = opmB + (size_t)g * 3;
            int mk0 = mrow[0], mk1 = mrow[1], mk2 = mrow[2];
            float w1 = wh1s[r];
            float e0 = w1 + wh2s[3 + r];
            float e1 = w1 + wh2s[4 + r];
            float e2 = w1 + wh2s[5 + r];
            e0 = e0 > 0.f ? e0 : ALPHA * e0;
            e1 = e1 > 0.f ? e1 : ALPHA * e1;
            e2 = e2 > 0.f ? e2 : ALPHA * e2;
            if (mk0 > 0) e0 = NEG_INF;
            if (mk1 > 0) e1 = NEG_INF;
            if (mk2 > 0) e2 = NEG_INF;
            float m = fmaxf(e0, fmaxf(e1, e2));
            float x0 = __expf(e0 - m), x1 = __expf(e1 - m), x2 = __expf(e2 - m);
            float inv = 1.f / (x0 + x1 + x2);
            float a0 = x0 * inv, a1 = x1 * inv, a2 = x2 * inv;
            int cb = (t & 31) << 3;
            ushort4 wm = *(const ushort4*)(&Bw[(r - 1) * 256 + (cb ^ (((r - 1) & 7) << 4))]);
            ushort4 w0 = *(const ushort4*)(&Bw[r * 256 + (cb ^ ((r & 7) << 4))]);
            ushort4 wp = *(const ushort4*)(&Bw[(r + 1) * 256 + (cb ^ (((r + 1) & 7) << 4))]);
            f32x4 res;
            res[0] = a0 * bf2f(wm.x) + a1 * bf2f(w0.x) + a2 * bf2f(wp.x);
            res[1] = a0 * bf2f(wm.y) + a1 * bf2f(w0.y) + a2 * bf2f(wp.y);
            res[2] = a0 * bf2f(wm.z) + a1 * bf2f(w0.z) + a2 * bf2f(wp.z);
            res[3] = a0 * bf2f(wm.w) + a1 * bf2f(w0.w) + a2 * bf2f(wp.w);
            *(f32x4*)(outB + (size_t)g * 128 + ((t & 31) << 2)) = res;
        }

        // ---- write staged next tile into Ah ----
        if (hn) {
            #pragma unroll
            for (int i = 0; i < 8; ++i) {
                int rl = (w << 4) + (i << 1) + (lane >> 5);
                ushort4 p4;
                p4.x = (unsigned short)fb(sreg[i][0]);
                p4.y = (unsigned short)fb(sreg[i][1]);
                p4.z = (unsigned short)fb(sreg[i][2]);
                p4.w = (unsigned short)fb(sreg[i][3]);
                *(ushort4*)(&Ah[rl * 256 + ((((lane & 31) << 3)) ^ ((rl & 7) << 4))]) = p4;
            }
        }
        __syncthreads();
    }
}

extern "C" void kernel_launch(void* const* d_in, const int* in_sizes, int n_in,
                              void* d_out, int out_size, void* d_ws, size_t ws_size,
                              hipStream_t stream) {
    const float* h   = (const float*)d_in[0];
    const int*   opm = (const int*)d_in[1];
    const float* W   = (const float*)d_in[2];
    const float* a   = (const float*)d_in[3];
    float* out = (float*)d_out;
    unsigned short* ws = (unsigned short*)d_ws;
    prep_w<<<9, 256, 0, stream>>>(W, a, ws);
    gat_fused<<<GRID, 512, 0, stream>>>(h, opm, ws, out);
}

// Round 7
// 60.493 us; speedup vs baseline: 3.2849x; 2.6101x over previous
//
#include <hip/hip_runtime.h>
#include <hip/hip_bf16.h>

typedef __attribute__((ext_vector_type(8))) short short8;
typedef __attribute__((ext_vector_type(4))) float f32x4;

#define ALPHA 0.2f
#define NEG_INF -9e15f
#define ROWS 64               // staged h rows = Wh rows per tile
#define OUT 62                // output rows per tile
#define NTILES 1058           // ceil(65536/62)
#define NB 4
#define NN 65536
#define TOT (NTILES * NB)     // 4232
#define GRID 512              // persistent, 2 blocks/CU

typedef __attribute__((address_space(3))) void as3_void;
typedef const __attribute__((address_space(1))) void as1_void;

__device__ __forceinline__ short fb(float x) {
    __hip_bfloat16 b = __float2bfloat16(x);
    return __builtin_bit_cast(short, b);
}
__device__ __forceinline__ float bf2f(unsigned short x) {
    union { unsigned int u; float f; } v; v.u = ((unsigned int)x) << 16;
    return v.f;
}

// prep: W -> bf16 B-fragment table (frag fi = kk*8+q, q = 16-col block) at
// shorts[0..16383]; [Wa1|Wa2|0..] column-fragment table at shorts[16384..].
__global__ __launch_bounds__(256) void prep_w(const float* __restrict__ W,
                                              const float* __restrict__ a,
                                              unsigned short* __restrict__ ws) {
    const int t = threadIdx.x;
    if (blockIdx.x < 8) {
        int qg = blockIdx.x * 256 + t;       // 0..2047
        int lane = qg & 63, fi = qg >> 6;
        int q = fi & 7, kk = fi >> 3;
        int n = q * 16 + (lane & 15);
        int k0 = kk * 32 + ((lane >> 4) & 3) * 8;
        short8 o;
        #pragma unroll
        for (int j = 0; j < 8; ++j) o[j] = fb(W[(k0 + j) * 128 + n]);
        *(short8*)(ws + (size_t)qg * 8) = o;
    } else {
        __shared__ float wa[2][128];
        {
            int k = t >> 1, sel = t & 1;
            const f32x4* wr4 = (const f32x4*)(W + k * 128);
            const f32x4* av4 = (const f32x4*)(a + sel * 128);
            float s = 0.f;
            #pragma unroll
            for (int c4 = 0; c4 < 32; ++c4) {
                f32x4 wv = wr4[c4], av = av4[c4];
                s += wv[0]*av[0] + wv[1]*av[1] + wv[2]*av[2] + wv[3]*av[3];
            }
            wa[sel][k] = s;
        }
        __syncthreads();
        {
            int lane = t & 63, kk = t >> 6;
            int l15 = lane & 15, lg = (lane >> 4) & 3;
            int k0 = kk * 32 + lg * 8;
            short8 o;
            #pragma unroll
            for (int j = 0; j < 8; ++j) o[j] = fb((l15 < 2) ? wa[l15][k0 + j] : 0.f);
            *(short8*)(ws + 16384 + (size_t)t * 8) = o;
        }
    }
}

// Persistent pipelined kernel, 256 threads, 64-row tiles, gload_lds staging.
__global__ __launch_bounds__(256, 2)
void gat_fused(const float* __restrict__ h, const int* __restrict__ opm,
               const unsigned short* __restrict__ ws, float* __restrict__ out) {
    __shared__ __align__(16) char Ah[2][32768];  // f32 h tile -> (reused) bf16 Wh
    __shared__ float wh1s[64];
    __shared__ float wh2s[72];                   // row r at 4+r
    __shared__ int maskL[192];

    const int t = threadIdx.x;
    const int lane = t & 63;
    const int w = t >> 6;
    const int l15 = lane & 15;
    const int lg = (lane >> 4) & 3;
    const int R = (w >> 1) << 5;       // row band 0 / 32
    const int ch = w & 1;              // col half 0 / 1

    // ---- hoist B fragments (loop-invariant registers) ----
    const short8* wsv  = (const short8*)ws;
    const short8* wsv2 = (const short8*)(ws + 16384);
    short8 bfr[4][4], bfr2[4];
    #pragma unroll
    for (int kk = 0; kk < 4; ++kk) {
        #pragma unroll
        for (int ni = 0; ni < 4; ++ni)
            bfr[kk][ni] = wsv[(size_t)(((kk << 3) + (ch << 2) + ni) * 64 + lane)];
        bfr2[kk] = wsv2[(size_t)((kk << 6) + lane)];
    }

    int ti = blockIdx.x;
    int mreg = 0;

    // ---- prologue: stage tile0 h + masks ----
    {
        int b = ti / NTILES;
        int tile = ti - b * NTILES;
        int base = tile * OUT - 1;
        const char* hC = (const char*)(h + (size_t)b * NN * 128);
        #pragma unroll
        for (int i = 0; i < 8; ++i) {
            int p = (w << 3) + i;                 // 0..31 (2 rows each)
            int r = (p << 1) + (lane >> 5);
            int g = base + r; if (g < 0) g += NN; else if (g >= NN) g -= NN;
            const char* src = hC + (size_t)g * 512 + ((((lane & 31) << 4)) ^ ((r & 7) << 4));
            __builtin_amdgcn_global_load_lds((as1_void*)src, (as3_void*)&Ah[0][p << 10], 16, 0, 0);
        }
        if (t < 186) {
            int idx = tile * OUT * 3 + t;
            if (idx > NN * 3 - 1) idx = NN * 3 - 1;
            mreg = opm[(size_t)b * NN * 3 + idx];
        }
    }
    __syncthreads();

    int cur = 0;
    for (; ti < TOT; ti += GRID) {
        const int b = ti / NTILES;
        const int tile = ti - b * NTILES;
        const int row_start = tile * OUT;
        const int base = row_start - 1;
        const int out_rows = min(OUT, NN - row_start);
        float* outB = out + (size_t)b * NN * 128;

        // masks for THIS tile (held in reg since last iter) -> LDS
        if (t < 186) maskL[t] = mreg;

        // ---- issue next tile's prefetch (stays in flight across compute) ----
        const int tn = ti + GRID;
        const bool hn = tn < TOT;
        if (hn) {
            int b2 = tn / NTILES;
            int tile2 = tn - b2 * NTILES;
            int base2 = tile2 * OUT - 1;
            const char* hC2 = (const char*)(h + (size_t)b2 * NN * 128);
            #pragma unroll
            for (int i = 0; i < 8; ++i) {
                int p = (w << 3) + i;
                int r = (p << 1) + (lane >> 5);
                int g = base2 + r; if (g < 0) g += NN; else if (g >= NN) g -= NN;
                const char* src = hC2 + (size_t)g * 512 + ((((lane & 31) << 4)) ^ ((r & 7) << 4));
                __builtin_amdgcn_global_load_lds((as1_void*)src, (as3_void*)&Ah[cur ^ 1][p << 10], 16, 0, 0);
            }
            if (t < 186) {
                int idx = tile2 * OUT * 3 + t;
                if (idx > NN * 3 - 1) idx = NN * 3 - 1;
                mreg = opm[(size_t)b2 * NN * 3 + idx];
            }
        }
        __builtin_amdgcn_sched_barrier(0);

        // ---- GEMM: Wh[64][128] = Ah[cur](f32->bf16) @ W ----
        f32x4 acc[2][4];
        f32x4 acc2[2];
        #pragma unroll
        for (int mi = 0; mi < 2; ++mi) {
            acc2[mi] = (f32x4){0.f, 0.f, 0.f, 0.f};
            #pragma unroll
            for (int ni = 0; ni < 4; ++ni)
                acc[mi][ni] = (f32x4){0.f, 0.f, 0.f, 0.f};
        }
        #pragma unroll
        for (int kk = 0; kk < 4; ++kk) {
            int kb = (kk << 7) + (lg << 5);
            short8 af[2];
            #pragma unroll
            for (int mi = 0; mi < 2; ++mi) {
                int m = R + (mi << 4) + l15;
                int sw = (m & 7) << 4;
                const char* bp = &Ah[cur][m * 512];
                f32x4 lo = *(const f32x4*)(bp + (kb ^ sw));
                f32x4 hi = *(const f32x4*)(bp + ((kb + 16) ^ sw));
                short8 v;
                v[0] = fb(lo[0]); v[1] = fb(lo[1]); v[2] = fb(lo[2]); v[3] = fb(lo[3]);
                v[4] = fb(hi[0]); v[5] = fb(hi[1]); v[6] = fb(hi[2]); v[7] = fb(hi[3]);
                af[mi] = v;
            }
            #pragma unroll
            for (int mi = 0; mi < 2; ++mi) {
                #pragma unroll
                for (int ni = 0; ni < 4; ++ni)
                    acc[mi][ni] = __builtin_amdgcn_mfma_f32_16x16x32_bf16(
                        af[mi], bfr[kk][ni], acc[mi][ni], 0, 0, 0);
                if (ch == 0)
                    acc2[mi] = __builtin_amdgcn_mfma_f32_16x16x32_bf16(
                        af[mi], bfr2[kk], acc2[mi], 0, 0, 0);
            }
        }

        // ---- lgkm-only barrier: everyone done reading Ah[cur]; vm stays in flight
        __builtin_amdgcn_sched_barrier(0);
        asm volatile("s_waitcnt lgkmcnt(0)" ::: "memory");
        __builtin_amdgcn_s_barrier();
        __builtin_amdgcn_sched_barrier(0);

        // ---- spill Wh (bf16, swizzled) into Ah[cur]; wh1/wh2 from acc2 ----
        {
            char* Bw = &Ah[cur][0];
            #pragma unroll
            for (int mi = 0; mi < 2; ++mi)
                #pragma unroll
                for (int ni = 0; ni < 4; ++ni) {
                    int col = (ch << 6) + (ni << 4) + l15;
                    #pragma unroll
                    for (int j = 0; j < 4; ++j) {
                        int row = R + (mi << 4) + (lg << 2) + j;
                        *(unsigned short*)(Bw + row * 256 + ((col << 1) ^ ((row & 7) << 4))) =
                            (unsigned short)fb(acc[mi][ni][j]);
                    }
                }
            if (ch == 0 && l15 < 2) {
                float* dst = (l15 == 0) ? wh1s : (wh2s + 4);
                #pragma unroll
                for (int mi = 0; mi < 2; ++mi)
                    #pragma unroll
                    for (int j = 0; j < 4; ++j)
                        dst[R + (mi << 4) + (lg << 2) + j] = acc2[mi][j];
            }
        }
        __builtin_amdgcn_sched_barrier(0);
        asm volatile("s_waitcnt lgkmcnt(0)" ::: "memory");
        __builtin_amdgcn_s_barrier();
        __builtin_amdgcn_sched_barrier(0);

        // ---- combine: inline softmax + coalesced f32x4 stores ----
        const char* Bw = &Ah[cur][0];
        #pragma unroll
        for (int it = 0; it < 8; ++it) {
            int r = 1 + (t >> 5) + (it << 3);
            if (r > out_rows) continue;
            int g = base + r;
            int mk0 = maskL[(r - 1) * 3];
            int mk1 = maskL[(r - 1) * 3 + 1];
            int mk2 = maskL[(r - 1) * 3 + 2];
            float w1 = wh1s[r];
            float e0 = w1 + wh2s[3 + r];
            float e1 = w1 + wh2s[4 + r];
            float e2 = w1 + wh2s[5 + r];
            e0 = e0 > 0.f ? e0 : ALPHA * e0;
            e1 = e1 > 0.f ? e1 : ALPHA * e1;
            e2 = e2 > 0.f ? e2 : ALPHA * e2;
            if (mk0 > 0) e0 = NEG_INF;
            if (mk1 > 0) e1 = NEG_INF;
            if (mk2 > 0) e2 = NEG_INF;
            float m = fmaxf(e0, fmaxf(e1, e2));
            float x0 = __expf(e0 - m), x1 = __expf(e1 - m), x2 = __expf(e2 - m);
            float inv = 1.f / (x0 + x1 + x2);
            float a0 = x0 * inv, a1 = x1 * inv, a2 = x2 * inv;
            int cb = (t & 31) << 3;
            ushort4 wm = *(const ushort4*)(Bw + (r - 1) * 256 + (cb ^ (((r - 1) & 7) << 4)));
            ushort4 w0 = *(const ushort4*)(Bw + r * 256 + (cb ^ ((r & 7) << 4)));
            ushort4 wp = *(const ushort4*)(Bw + (r + 1) * 256 + (cb ^ (((r + 1) & 7) << 4)));
            f32x4 res;
            res[0] = a0 * bf2f(wm.x) + a1 * bf2f(w0.x) + a2 * bf2f(wp.x);
            res[1] = a0 * bf2f(wm.y) + a1 * bf2f(w0.y) + a2 * bf2f(wp.y);
            res[2] = a0 * bf2f(wm.z) + a1 * bf2f(w0.z) + a2 * bf2f(wp.z);
            res[3] = a0 * bf2f(wm.w) + a1 * bf2f(w0.w) + a2 * bf2f(wp.w);
            *(f32x4*)(outB + (size_t)g * 128 + ((t & 31) << 2)) = res;
        }

        // ---- full drain: next tile's h is in LDS after this ----
        __syncthreads();
        cur ^= 1;
    }
}

extern "C" void kernel_launch(void* const* d_in, const int* in_sizes, int n_in,
                              void* d_out, int out_size, void* d_ws, size_t ws_size,
                              hipStream_t stream) {
    const float* h   = (const float*)d_in[0];
    const int*   opm = (const int*)d_in[1];
    const float* W   = (const float*)d_in[2];
    const float* a   = (const float*)d_in[3];
    float* out = (float*)d_out;
    unsigned short* ws = (unsigned short*)d_ws;
    prep_w<<<9, 256, 0, stream>>>(W, a, ws);
    gat_fused<<<GRID, 256, 0, stream>>>(h, opm, ws, out);
}